// Round 5
// baseline (135.661 us; speedup 1.0000x reference)
//
#include <hip/hip_runtime.h>
#include <hip/hip_bf16.h>

#define DDIM 512
#define NROWS 6144
#define BM 64
#define BN 128
#define BK 32
#define KSTEPS (DDIM / BK)  // 16

typedef __attribute__((ext_vector_type(8))) short short8;
typedef __attribute__((ext_vector_type(4))) float f32x4;

#define GLDS16(g, s)                                          \
  __builtin_amdgcn_global_load_lds(                           \
      (const __attribute__((address_space(1))) void*)(g),     \
      (__attribute__((address_space(3))) void*)(s), 16, 0, 0)

// ---------------------------------------------------------------------------
// Fold the 4 [512,512] k-blocks of W [2048,512] (sum), transpose to Wt[n][k],
// cast bf16.  Vectorized: float4 global reads, ushort4 (4x bf16) writes.
// Tile = 32 k-rows x 64 n-cols; grid (16, 8, 2) = 256 blocks.
// ---------------------------------------------------------------------------
__global__ __launch_bounds__(256) void prep_w(
    const float* __restrict__ Wcc, const float* __restrict__ Wcp,
    __hip_bfloat16* __restrict__ Wt) {
    const float* W = blockIdx.z ? Wcp : Wcc;
    unsigned short* o = (unsigned short*)Wt + (size_t)blockIdx.z * DDIM * DDIM;
    __shared__ float lds[32][65];
    const int k0 = blockIdx.x * 32, n0 = blockIdx.y * 64;
    #pragma unroll
    for (int u = 0; u < 2; ++u) {
        int idx = u * 256 + threadIdx.x;
        int kk = idx >> 4, c = idx & 15;
        float4 s = {0.f, 0.f, 0.f, 0.f};
        #pragma unroll
        for (int i = 0; i < 4; ++i) {
            float4 v = *(const float4*)&W[(size_t)(i * DDIM + k0 + kk) * DDIM + n0 + c * 4];
            s.x += v.x; s.y += v.y; s.z += v.z; s.w += v.w;
        }
        lds[kk][c * 4 + 0] = s.x;
        lds[kk][c * 4 + 1] = s.y;
        lds[kk][c * 4 + 2] = s.z;
        lds[kk][c * 4 + 3] = s.w;
    }
    __syncthreads();
    #pragma unroll
    for (int u = 0; u < 2; ++u) {
        int idx = u * 256 + threadIdx.x;
        int nr = idx >> 3, kc = idx & 7;
        ushort4 p;
        #pragma unroll
        for (int j = 0; j < 4; ++j) {
            __hip_bfloat16 h = __float2bfloat16(lds[kc * 4 + j][nr]);
            ((unsigned short*)&p)[j] = *(unsigned short*)&h;
        }
        *(ushort4*)&o[(size_t)(n0 + nr) * DDIM + k0 + kc * 4] = p;
    }
}

// ---------------------------------------------------------------------------
// C[6144,512] = A_f32 @ W + bias.  2-buffer LDS (32 KB -> 5 blocks/CU, 20
// waves/CU), depth-1 prefetch, one raw s_barrier + vmcnt(0) per K-step.
// At the wait point only stage t's 4 glds are outstanding, so vmcnt(0) is a
// counted wait for exactly stage t.  STAGE(t+1) after the barrier overwrites
// the buffer computed at t-1: safe because every ds_read of it was consumed
// by an MFMA (compiler lgkmcnt) before its wave reached barrier t.
// Tile 64x128, 4 waves (wave tile 32x64).  Grid (96,4,2) = 768 = 5/CU.
// Swizzle (rule #21): linear glds dest + pre-swizzled source + swizzled read.
//   A row = 128 B = 8 slots, slot ^= (row & 7)        -> 2-way (free)
//   B row =  64 B = 4 slots, slot ^= ((row>>1) & 3)   -> 2-way (free)
// ---------------------------------------------------------------------------
__global__ __launch_bounds__(256, 5) void gemm_bias(
    const float* __restrict__ Aat, const float* __restrict__ Aam,
    const __hip_bfloat16* __restrict__ Wtall,
    const float* __restrict__ bias0, const float* __restrict__ bias1,
    float* __restrict__ C) {
  __shared__ float As[2][BM * BK];           // 2 x 8 KB
  __shared__ unsigned short Bs[2][BN * BK];  // 2 x 8 KB

  const int z = blockIdx.z;
  const float* A = z ? Aam : Aat;
  const unsigned short* Wt = (const unsigned short*)Wtall + (size_t)z * DDIM * DDIM;
  const float* bias = z ? bias1 : bias0;
  float* Cz = C + (size_t)z * NROWS * DDIM;

  const int tid = threadIdx.x;
  const int w = tid >> 6, l = tid & 63;
  const int m0 = blockIdx.x * BM;
  const int n0 = blockIdx.y * BN;

  // staging sources (pre-swizzled) + wave-uniform LDS offsets
  const float* srcA0;
  const float* srcA1;
  const unsigned short* srcB0;
  const unsigned short* srcB1;
  {
    int r0 = w * 16 + (l >> 3);           // A instr 0: rows w*16 .. +7
    int r1 = r0 + 8;                      // A instr 1
    srcA0 = A + (size_t)(m0 + r0) * DDIM + (((l & 7) ^ (r0 & 7)) << 2);
    srcA1 = A + (size_t)(m0 + r1) * DDIM + (((l & 7) ^ (r1 & 7)) << 2);
    int q0 = w * 32 + (l >> 2);           // B instr 0: rows w*32 .. +15
    int q1 = q0 + 16;                     // B instr 1
    srcB0 = Wt + (size_t)(n0 + q0) * DDIM + (((l & 3) ^ ((q0 >> 1) & 3)) << 3);
    srcB1 = Wt + (size_t)(n0 + q1) * DDIM + (((l & 3) ^ ((q1 >> 1) & 3)) << 3);
  }
  const unsigned ldsA0 = (w * 2 + 0) * 256, ldsA1 = (w * 2 + 1) * 256;
  const unsigned ldsB0 = (w * 2 + 0) * 512, ldsB1 = (w * 2 + 1) * 512;

#define STAGE(buf, kk)                                 \
  do {                                                 \
    GLDS16(srcA0 + (kk) * BK, &As[buf][ldsA0]);        \
    GLDS16(srcA1 + (kk) * BK, &As[buf][ldsA1]);        \
    GLDS16(srcB0 + (kk) * BK, &Bs[buf][ldsB0]);        \
    GLDS16(srcB1 + (kk) * BK, &Bs[buf][ldsB1]);        \
  } while (0)

  f32x4 acc[2][4];
  #pragma unroll
  for (int i = 0; i < 2; ++i)
    #pragma unroll
    for (int j = 0; j < 4; ++j) acc[i][j] = (f32x4){0.f, 0.f, 0.f, 0.f};

  const int s0 = (l >> 4) * 2;   // A 16B-slot pair base (k-group)
  const int bs = (l >> 4);       // B 16B slot (k-group)
  const int lr = l & 15;

#define COMPUTE(buf)                                                          \
  do {                                                                        \
    short8 afr[2];                                                            \
    _Pragma("unroll")                                                         \
    for (int tm = 0; tm < 2; ++tm) {                                          \
      int r = (w >> 1) * 32 + tm * 16 + lr;                                   \
      f32x4 x0 = *(const f32x4*)&As[buf][r * BK + (((s0 + 0) ^ (r & 7)) << 2)]; \
      f32x4 x1 = *(const f32x4*)&As[buf][r * BK + (((s0 + 1) ^ (r & 7)) << 2)]; \
      float xv[8] = {x0[0], x0[1], x0[2], x0[3], x1[0], x1[1], x1[2], x1[3]}; \
      _Pragma("unroll")                                                       \
      for (int e = 0; e < 8; ++e) {                                           \
        __hip_bfloat16 h = __float2bfloat16(xv[e]);                           \
        afr[tm][e] = *(short*)&h;                                             \
      }                                                                       \
    }                                                                         \
    _Pragma("unroll")                                                         \
    for (int tn = 0; tn < 4; ++tn) {                                          \
      int r = (w & 1) * 64 + tn * 16 + lr;                                    \
      short8 bf = *(const short8*)&Bs[buf][r * BK + ((bs ^ ((r >> 1) & 3)) << 3)]; \
      acc[0][tn] = __builtin_amdgcn_mfma_f32_16x16x32_bf16(afr[0], bf, acc[0][tn], 0, 0, 0); \
      acc[1][tn] = __builtin_amdgcn_mfma_f32_16x16x32_bf16(afr[1], bf, acc[1][tn], 0, 0, 0); \
    }                                                                         \
  } while (0)

  // prologue: one stage in flight
  STAGE(0, 0);

  #pragma unroll
  for (int t = 0; t < KSTEPS; ++t) {
    asm volatile("s_waitcnt vmcnt(0)" ::: "memory");   // stage t landed
    __builtin_amdgcn_s_barrier();
    if (t + 1 < KSTEPS) STAGE((t + 1) & 1, t + 1);
    COMPUTE(t & 1);
  }

  // epilogue
  const int rg = (l >> 4) * 4;
  #pragma unroll
  for (int tn = 0; tn < 4; ++tn) {
    const int col = n0 + (w & 1) * 64 + tn * 16 + lr;
    const float bv = bias[col];
    #pragma unroll
    for (int tm = 0; tm < 2; ++tm) {
      const int row = m0 + (w >> 1) * 32 + tm * 16 + rg;
      #pragma unroll
      for (int r = 0; r < 4; ++r)
        Cz[(size_t)(row + r) * DDIM + col] = acc[tm][tn][r] + bv;
    }
  }
#undef STAGE
#undef COMPUTE
}

extern "C" void kernel_launch(void* const* d_in, const int* in_sizes, int n_in,
                              void* d_out, int out_size, void* d_ws, size_t ws_size,
                              hipStream_t stream) {
    const float* atoms = (const float*)d_in[0];   // [6144,512]
    const float* amino = (const float*)d_in[1];   // [6144,512]
    const float* Wcc   = (const float*)d_in[15];  // [2048,512]
    const float* bcc   = (const float*)d_in[16];  // [512]
    const float* Wcp   = (const float*)d_in[17];  // [2048,512]
    const float* bcp   = (const float*)d_in[18];  // [512]
    float* out = (float*)d_out;

    __hip_bfloat16* Wt = (__hip_bfloat16*)d_ws;   // [2][512][512] bf16 = 1 MB

    dim3 fgrid(DDIM / 32, DDIM / 64, 2);
    prep_w<<<fgrid, 256, 0, stream>>>(Wcc, Wcp, Wt);

    dim3 ggrid(NROWS / BM, DDIM / BN, 2);
    gemm_bias<<<ggrid, 256, 0, stream>>>(atoms, amino, Wt, bcc, bcp, out);
}